// Round 9
// baseline (407.399 us; speedup 1.0000x reference)
//
#include <hip/hip_runtime.h>
#include <hip/hip_bf16.h>
#include <math.h>

#define F_IN 128
#define F_HID 64
#define F_OUT 40
#define BN_EPS 1e-5f

__device__ __forceinline__ float bflo(unsigned u) { return __uint_as_float(u << 16); }
__device__ __forceinline__ float bfhi(unsigned u) { return __uint_as_float(u & 0xffff0000u); }

// ---- in-degree histogram; atomic return = edge's rank within its segment ----
__global__ void k_deg(const int* __restrict__ col, int E,
                      int* __restrict__ deg, int* __restrict__ rank) {
    int e = blockIdx.x * blockDim.x + threadIdx.x;
    if (e < E) rank[e] = atomicAdd(deg + col[e], 1);
}

// ---- segment allocation: block scan, one cursor atomic per block ----
__global__ __launch_bounds__(256) void k_offsets(
        const int* __restrict__ deg, int* __restrict__ off,
        int* __restrict__ endp, float* __restrict__ dinv,
        int* __restrict__ cursor, int n) {
    int i = blockIdx.x * 256 + threadIdx.x;
    int lane = threadIdx.x & 63, wv = threadIdx.x >> 6;
    int d = (i < n) ? deg[i] : 0;
    int scan = d;
    #pragma unroll
    for (int o = 1; o < 64; o <<= 1) {
        int t = __shfl_up(scan, o);
        if (lane >= o) scan += t;
    }
    __shared__ int wsum[4];
    if (lane == 63) wsum[wv] = scan;
    __syncthreads();
    if (threadIdx.x == 0) {
        int s0 = wsum[0], s1 = wsum[1], s2 = wsum[2], s3 = wsum[3];
        int base = atomicAdd(cursor, s0 + s1 + s2 + s3);
        wsum[0] = base; wsum[1] = base + s0;
        wsum[2] = base + s0 + s1; wsum[3] = base + s0 + s1 + s2;
    }
    __syncthreads();
    if (i < n) {
        int b = wsum[wv] + scan - d;
        off[i] = b;
        endp[i] = b + d;
        dinv[i] = rsqrtf((float)d + 1.0f);  // +1 self-loop
    }
}

// ---- atomic-free CSR scatter, 2 phases by destination half (L2-fit stores) ----
__global__ void k_edges(const int* __restrict__ row, const int* __restrict__ col,
                        const int* __restrict__ off, const int* __restrict__ rank,
                        int* __restrict__ srcs, int E, int half) {
    int e = blockIdx.x * blockDim.x + threadIdx.x;
    if (e >= E) return;
    int c = col[e];
    if ((c < half) != (blockIdx.y == 0)) return;
    srcs[off[c] + rank[e]] = row[e];
}

// ---- zero pad rows (row n of every region) used by idle gather lanes ----
__global__ void k_zero(unsigned* __restrict__ h1z, unsigned* __restrict__ h2z, int n) {
    size_t R1 = ((size_t)n + 1) * 8;
    size_t R2 = ((size_t)n + 1) * 10;
    int t = threadIdx.x;
    if (t < 32) h1z[(size_t)(t >> 3) * R1 + (size_t)n * 8 + (t & 7)] = 0u;
    if (t < 20) h2z[(size_t)(t / 10) * R2 + (size_t)n * 10 + (t % 10)] = 0u;
}

// ---- h1' = dinv * (BN(x) @ W1); lane=node, W1 rows as uniform scalar operands.
//      Output in 4 feature-blocked regions of (n+1)*32B (L2-fit gather slices). ----
__global__ __launch_bounds__(64) void k_gemm1(
        const float* __restrict__ x, const float* __restrict__ gamma,
        const float* __restrict__ beta, const float* __restrict__ mean,
        const float* __restrict__ var, const float* __restrict__ W1,
        const float* __restrict__ dinv, unsigned* __restrict__ h1u, int n) {
    __shared__ float xl[64 * 65];
    int lane = threadIdx.x;
    int nb = blockIdx.x * 64;
    float acc[F_HID];
    #pragma unroll
    for (int f = 0; f < F_HID; ++f) acc[f] = 0.f;
    int f4 = (lane & 15) * 4;
    int tn = lane >> 4;
    for (int ph = 0; ph < 2; ++ph) {
        int fb = ph * 64;
        float4 vr = *(const float4*)(var + fb + f4);
        float4 gm = *(const float4*)(gamma + fb + f4);
        float4 be = *(const float4*)(beta + fb + f4);
        float4 mn = *(const float4*)(mean + fb + f4);
        float sx = rsqrtf(vr.x + BN_EPS) * gm.x, tx = be.x - mn.x * sx;
        float sy = rsqrtf(vr.y + BN_EPS) * gm.y, ty = be.y - mn.y * sy;
        float sz = rsqrtf(vr.z + BN_EPS) * gm.z, tz = be.z - mn.z * sz;
        float sw = rsqrtf(vr.w + BN_EPS) * gm.w, tw = be.w - mn.w * sw;
        if (ph) __syncthreads();
        for (int it = 0; it < 16; ++it) {
            int r = it * 4 + tn;
            int node = nb + r;
            float4 v = make_float4(0.f, 0.f, 0.f, 0.f);
            if (node < n) v = *(const float4*)(x + (long)node * F_IN + fb + f4);
            int b = r * 65 + f4;
            xl[b + 0] = v.x * sx + tx;
            xl[b + 1] = v.y * sy + ty;
            xl[b + 2] = v.z * sz + tz;
            xl[b + 3] = v.w * sw + tw;
        }
        __syncthreads();
        for (int k = 0; k < 64; ++k) {
            float xv = xl[lane * 65 + k];
            const float* wr = W1 + (fb + k) * F_HID;
            #pragma unroll
            for (int f = 0; f < F_HID; ++f) acc[f] = fmaf(xv, wr[f], acc[f]);
        }
    }
    int node = nb + lane;
    if (node < n) {
        float d = dinv[node];
        size_t R1 = ((size_t)n + 1) * 8;
        #pragma unroll
        for (int r = 0; r < 4; ++r) {
            #pragma unroll
            for (int t = 0; t < 8; ++t) {
                __hip_bfloat162 pr;
                pr.x = __float2bfloat16(acc[r * 16 + 2 * t] * d);
                pr.y = __float2bfloat16(acc[r * 16 + 2 * t + 1] * d);
                h1u[(size_t)r * R1 + (long)node * 8 + t] = *(unsigned*)&pr;
            }
        }
    }
}

// ---- conv1: feature-blocked gather pass (gridDim.y = 4 slices).
//      8 nodes/wave, 8 lanes/node, 4B/lane; slice = 3.2MB -> L2-resident. ----
__global__ __launch_bounds__(256, 8) void k_conv1(
        const unsigned* __restrict__ h1u, const int* __restrict__ srcs,
        const int* __restrict__ off, const int* __restrict__ endp,
        const float* __restrict__ dinv, const float* __restrict__ b1,
        unsigned* __restrict__ hu, int n) {
    int lane = threadIdx.x & 63;
    int g = lane >> 3, f = lane & 7, gb = g * 8;
    const unsigned* base = h1u + (size_t)blockIdx.y * (((size_t)n + 1) * 8);
    int node = blockIdx.x * 32 + (threadIdx.x >> 6) * 8 + g;
    int nodec = (node < n) ? node : n;
    int j = (node < n) ? off[node] : 0;
    int e = (node < n) ? endp[node] : 0;
    float a0 = 0.f, a1 = 0.f;
    while (__any(j < e)) {
        int cnt = e - j;
        cnt = cnt < 0 ? 0 : (cnt > 8 ? 8 : cnt);
        int srcv = n;                        // pad row (zeroed)
        if (f < cnt) srcv = srcs[j + f];
        #pragma unroll
        for (int k = 0; k < 8; ++k) {
            int s = __shfl(srcv, gb + k);
            unsigned u = base[(long)s * 8 + f];
            a0 += bflo(u);
            a1 += bfhi(u);
        }
        j += cnt;
    }
    unsigned us = base[(long)nodec * 8 + f];     // self row (pre-scaled)
    float d = (node < n) ? dinv[node] : 0.f;
    float2 bb = ((const float2*)b1)[blockIdx.y * 8 + f];
    float h0 = fmaxf(d * (a0 + bflo(us)) + bb.x, 0.f);
    float h1 = fmaxf(d * (a1 + bfhi(us)) + bb.y, 0.f);
    if (node < n) {
        __hip_bfloat162 pr;
        pr.x = __float2bfloat16(h0);
        pr.y = __float2bfloat16(h1);
        hu[(long)node * 32 + blockIdx.y * 8 + f] = *(unsigned*)&pr;  // row-major h
    }
}

// ---- h2' = dinv * (h @ W2); output in 2 feature-blocked regions of (n+1)*40B ----
__global__ __launch_bounds__(64) void k_gemm2(
        const unsigned* __restrict__ h32, const float* __restrict__ W2,
        const float* __restrict__ dinv, unsigned* __restrict__ h2u, int n) {
    __shared__ float xl[64 * 66];
    int lane = threadIdx.x;
    int nb = blockIdx.x * 64;
    int tn = lane >> 5;
    int q = lane & 31;
    for (int it = 0; it < 32; ++it) {
        int r = it * 2 + tn;
        int node = nb + r;
        unsigned u = 0;
        if (node < n) u = h32[(long)node * 32 + q];
        xl[r * 66 + 2 * q]     = bflo(u);
        xl[r * 66 + 2 * q + 1] = bfhi(u);
    }
    __syncthreads();
    float acc[F_OUT];
    #pragma unroll
    for (int f = 0; f < F_OUT; ++f) acc[f] = 0.f;
    for (int k = 0; k < F_HID; ++k) {
        float xv = xl[lane * 66 + k];
        const float* wr = W2 + k * F_OUT;
        #pragma unroll
        for (int f = 0; f < F_OUT; ++f) acc[f] = fmaf(xv, wr[f], acc[f]);
    }
    int node = nb + lane;
    if (node < n) {
        float d = dinv[node];
        size_t R2 = ((size_t)n + 1) * 10;
        #pragma unroll
        for (int r = 0; r < 2; ++r) {
            #pragma unroll
            for (int t = 0; t < 10; ++t) {
                __hip_bfloat162 pr;
                pr.x = __float2bfloat16(acc[r * 20 + 2 * t] * d);
                pr.y = __float2bfloat16(acc[r * 20 + 2 * t + 1] * d);
                h2u[(size_t)r * R2 + (long)node * 10 + t] = *(unsigned*)&pr;
            }
        }
    }
}

// ---- conv2: feature-blocked gather pass (gridDim.y = 2 slices).
//      6 nodes/wave, 10 lanes/node, 4B/lane; logits -> fp32 tmp. ----
__global__ __launch_bounds__(256, 8) void k_conv2(
        const unsigned* __restrict__ h2u, const int* __restrict__ srcs,
        const int* __restrict__ off, const int* __restrict__ endp,
        const float* __restrict__ dinv, const float* __restrict__ b2,
        float* __restrict__ tmp, int n) {
    int lane = threadIdx.x & 63;
    bool lact = lane < 60;
    int g = lane / 10; if (g > 5) g = 5;     // lanes 60-63 shadow group 5
    int f = lane % 10;
    int gb = g * 10;
    const unsigned* base = h2u + (size_t)blockIdx.y * (((size_t)n + 1) * 10);
    int node = blockIdx.x * 24 + (threadIdx.x >> 6) * 6 + g;
    if (!lact) node = n;                     // inert lanes -> pad
    int nodec = (node < n) ? node : n;
    int j = (node < n) ? off[node] : 0;
    int e = (node < n) ? endp[node] : 0;
    float a0 = 0.f, a1 = 0.f;
    while (__any(j < e)) {
        int cnt = e - j;
        cnt = cnt < 0 ? 0 : (cnt > 10 ? 10 : cnt);
        int srcv = n;
        if (f < cnt && lact) srcv = srcs[j + f];
        #pragma unroll
        for (int k = 0; k < 10; ++k) {
            int s = __shfl(srcv, gb + k);
            unsigned u = base[(long)s * 10 + f];
            a0 += bflo(u);
            a1 += bfhi(u);
        }
        j += cnt;
    }
    unsigned us = base[(long)nodec * 10 + f];
    float d = (node < n) ? dinv[node] : 0.f;
    float2 bb = ((const float2*)b2)[blockIdx.y * 10 + f];
    float v0 = d * (a0 + bflo(us)) + bb.x;
    float v1 = d * (a1 + bfhi(us)) + bb.y;
    if (node < n && lact) {
        float2 o;
        o.x = v0; o.y = v1;
        *(float2*)(tmp + (long)node * F_OUT + blockIdx.y * 20 + 2 * f) = o;
    }
}

// ---- log_softmax over the 40 logits of each node; wave per node ----
__global__ __launch_bounds__(256) void k_lsm(const float* __restrict__ tmp,
                                             float* __restrict__ out, int n) {
    int t = blockIdx.x * 256 + threadIdx.x;
    int node = t >> 6, lane = t & 63;
    if (node >= n) return;
    float v = (lane < F_OUT) ? tmp[(long)node * F_OUT + lane] : -INFINITY;
    float m = v;
    #pragma unroll
    for (int o = 32; o > 0; o >>= 1) m = fmaxf(m, __shfl_xor(m, o));
    float ex = (lane < F_OUT) ? expf(v - m) : 0.f;
    float s = ex;
    #pragma unroll
    for (int o = 32; o > 0; o >>= 1) s += __shfl_xor(s, o);
    float lse = logf(s) + m;
    if (lane < F_OUT) out[(long)node * F_OUT + lane] = v - lse;
}

extern "C" void kernel_launch(void* const* d_in, const int* in_sizes, int n_in,
                              void* d_out, int out_size, void* d_ws, size_t ws_size,
                              hipStream_t stream) {
    const float* x     = (const float*)d_in[0];
    const int*   ei    = (const int*)d_in[1];
    const float* gamma = (const float*)d_in[2];
    const float* beta  = (const float*)d_in[3];
    const float* rmean = (const float*)d_in[4];
    const float* rvar  = (const float*)d_in[5];
    const float* W1    = (const float*)d_in[6];
    const float* b1    = (const float*)d_in[7];
    const float* W2    = (const float*)d_in[8];
    const float* b2    = (const float*)d_in[9];
    float* out = (float*)d_out;

    int n = in_sizes[0] / F_IN;
    int E = in_sizes[1] / 2;
    const int* row = ei;       // edge_index[0] = source
    const int* col = ei + E;   // edge_index[1] = target

    int*   deg    = (int*)d_ws;
    int*   off    = deg + n;
    int*   endp   = off + n;
    float* dinv   = (float*)(endp + n);
    int*   cursor = (int*)(dinv + n);                 // 4 ints (16B alignment)
    int*   rank   = cursor + 4;                       // E ints
    int*   srcs   = rank + E;                         // E ints
    unsigned* h1u = (unsigned*)(srcs + E);            // 4 regions x (n+1)*8 dwords
    unsigned* hu  = h1u + 4 * (((size_t)n + 1) * 8);  // n*32 dwords (row-major h)
    unsigned* h2u = hu + (size_t)n * 32;              // 2 regions x (n+1)*10 dwords
    float* tmp    = (float*)h1u;                      // n*40 fp32, aliases dead h1u/hu

    hipMemsetAsync(deg, 0, (size_t)n * sizeof(int), stream);
    hipMemsetAsync(cursor, 0, 4 * sizeof(int), stream);

    k_deg    <<<(E + 255) / 256, 256, 0, stream>>>(col, E, deg, rank);
    k_offsets<<<(n + 255) / 256, 256, 0, stream>>>(deg, off, endp, dinv, cursor, n);
    dim3 ge((E + 255) / 256, 2);
    k_edges  <<<ge, 256, 0, stream>>>(row, col, off, rank, srcs, E, n / 2);
    k_zero   <<<1, 64, 0, stream>>>(h1u, h2u, n);

    k_gemm1<<<(n + 63) / 64, 64, 0, stream>>>(x, gamma, beta, rmean, rvar, W1,
                                              dinv, h1u, n);
    dim3 g1((n + 31) / 32, 4);
    k_conv1<<<g1, 256, 0, stream>>>(h1u, srcs, off, endp, dinv, b1, hu, n);
    k_gemm2<<<(n + 63) / 64, 64, 0, stream>>>(hu, W2, dinv, h2u, n);
    dim3 g2((n + 23) / 24, 2);
    k_conv2<<<g2, 256, 0, stream>>>(h2u, srcs, off, endp, dinv, b2, tmp, n);
    k_lsm  <<<(n + 3) / 4, 256, 0, stream>>>(tmp, out, n);
}

// Round 10
// 363.155 us; speedup vs baseline: 1.1218x; 1.1218x over previous
//
#include <hip/hip_runtime.h>
#include <hip/hip_bf16.h>
#include <math.h>

#define F_IN 128
#define F_HID 64
#define F_OUT 40
#define BN_EPS 1e-5f

typedef __attribute__((ext_vector_type(8))) short short8;
typedef __attribute__((ext_vector_type(4))) float f32x4;

__device__ __forceinline__ float bflo(unsigned u) { return __uint_as_float(u << 16); }
__device__ __forceinline__ float bfhi(unsigned u) { return __uint_as_float(u & 0xffff0000u); }
__device__ __forceinline__ unsigned pack2(float a, float b) {
    __hip_bfloat162 p;
    p.x = __float2bfloat16(a);
    p.y = __float2bfloat16(b);
    return *(unsigned*)&p;
}

// ---- in-degree histogram; atomic return = edge's rank within its segment ----
__global__ void k_deg(const int* __restrict__ col, int E,
                      int* __restrict__ deg, int* __restrict__ rank) {
    int e = blockIdx.x * blockDim.x + threadIdx.x;
    if (e < E) rank[e] = atomicAdd(deg + col[e], 1);
}

// ---- segment allocation: block scan, one cursor atomic per block ----
__global__ __launch_bounds__(256) void k_offsets(
        const int* __restrict__ deg, int* __restrict__ off,
        int* __restrict__ endp, float* __restrict__ dinv,
        int* __restrict__ cursor, int n) {
    int i = blockIdx.x * 256 + threadIdx.x;
    int lane = threadIdx.x & 63, wv = threadIdx.x >> 6;
    int d = (i < n) ? deg[i] : 0;
    int scan = d;
    #pragma unroll
    for (int o = 1; o < 64; o <<= 1) {
        int t = __shfl_up(scan, o);
        if (lane >= o) scan += t;
    }
    __shared__ int wsum[4];
    if (lane == 63) wsum[wv] = scan;
    __syncthreads();
    if (threadIdx.x == 0) {
        int s0 = wsum[0], s1 = wsum[1], s2 = wsum[2], s3 = wsum[3];
        int base = atomicAdd(cursor, s0 + s1 + s2 + s3);
        wsum[0] = base; wsum[1] = base + s0;
        wsum[2] = base + s0 + s1; wsum[3] = base + s0 + s1 + s2;
    }
    __syncthreads();
    if (i < n) {
        int b = wsum[wv] + scan - d;
        off[i] = b;
        endp[i] = b + d;
        dinv[i] = rsqrtf((float)d + 1.0f);  // +1 self-loop
    }
}

// ---- atomic-free CSR scatter, 2 phases by destination half (L2-fit stores) ----
__global__ void k_edges(const int* __restrict__ row, const int* __restrict__ col,
                        const int* __restrict__ off, const int* __restrict__ rank,
                        int* __restrict__ srcs, int E, int half) {
    int e = blockIdx.x * blockDim.x + threadIdx.x;
    if (e >= E) return;
    int c = col[e];
    if ((c < half) != (blockIdx.y == 0)) return;
    srcs[off[c] + rank[e]] = row[e];
}

// ---- zero pad rows (row n of every region) used by idle gather lanes ----
__global__ void k_zero(unsigned* __restrict__ h1z, unsigned* __restrict__ h2z, int n) {
    size_t R1 = ((size_t)n + 1) * 8;
    size_t R2 = ((size_t)n + 1) * 10;
    int t = threadIdx.x;
    if (t < 32) h1z[(size_t)(t >> 3) * R1 + (size_t)n * 8 + (t & 7)] = 0u;
    if (t < 20) h2z[(size_t)(t / 10) * R2 + (size_t)n * 10 + (t % 10)] = 0u;
}

// ---- h1' = dinv * (BN(x) @ W1) via MFMA bf16.
//      Block = 256 thr = 4 waves, one 64-node tile. W1 B-frags in VGPRs,
//      BN(x) bf16 tile in LDS. Output: 4 feature-blocked regions. ----
__global__ __launch_bounds__(256) void k_gemm1(
        const float* __restrict__ x, const float* __restrict__ gamma,
        const float* __restrict__ beta, const float* __restrict__ mean,
        const float* __restrict__ var, const float* __restrict__ W1,
        const float* __restrict__ dinv, unsigned* __restrict__ h1u, int n) {
    __shared__ unsigned short xt[64 * 136];     // 64 rows x 272B (pad 8 bf16)
    __shared__ float bs[F_IN], bt[F_IN];
    int t = threadIdx.x;
    if (t < F_IN) {
        float s = rsqrtf(var[t] + BN_EPS) * gamma[t];
        bs[t] = s;
        bt[t] = beta[t] - mean[t] * s;
    }
    int lane = t & 63, wv = t >> 6;
    int quad = lane >> 4, c = lane & 15;
    // B-fragments: Bf[nt][ks], elem j = W1[ks*32+quad*8+j][nt*16+c] as bf16
    short8 Bf[4][4];
    #pragma unroll
    for (int nt = 0; nt < 4; ++nt)
        #pragma unroll
        for (int ks = 0; ks < 4; ++ks) {
            short8 v;
            #pragma unroll
            for (int j = 0; j < 8; ++j) {
                int k = ks * 32 + quad * 8 + j;
                __hip_bfloat16 hb = __float2bfloat16(W1[k * F_HID + nt * 16 + c]);
                v[j] = *(short*)&hb;
            }
            Bf[nt][ks] = v;
        }
    __syncthreads();                            // bs/bt ready
    int nb = blockIdx.x * 64;
    // stage 64 BN(x) rows as bf16 (coalesced float4 loads)
    #pragma unroll
    for (int it = 0; it < 8; ++it) {
        int i = t + 256 * it;                   // float4 slot: 2048 total
        int node = i >> 5, k4 = i & 31;
        int gn = nb + node;
        float4 v = make_float4(0.f, 0.f, 0.f, 0.f);
        if (gn < n) v = *(const float4*)(x + (size_t)gn * F_IN + k4 * 4);
        float4 sv = *(const float4*)(bs + k4 * 4);
        float4 tv = *(const float4*)(bt + k4 * 4);
        unsigned u0 = pack2(v.x * sv.x + tv.x, v.y * sv.y + tv.y);
        unsigned u1 = pack2(v.z * sv.z + tv.z, v.w * sv.w + tv.w);
        *(uint2*)(xt + node * 136 + k4 * 4) = make_uint2(u0, u1);
    }
    __syncthreads();
    // wave wv: nodes [nb + wv*16, +16); A frag: m=c, k=quad*8+j (+32*ks)
    const unsigned short* arow = xt + (wv * 16 + c) * 136;
    f32x4 acc[4] = {f32x4{0.f,0.f,0.f,0.f}, f32x4{0.f,0.f,0.f,0.f},
                    f32x4{0.f,0.f,0.f,0.f}, f32x4{0.f,0.f,0.f,0.f}};
    #pragma unroll
    for (int ks = 0; ks < 4; ++ks) {
        short8 af = *(const short8*)(arow + ks * 32 + quad * 8);  // ds_read_b128
        #pragma unroll
        for (int nt = 0; nt < 4; ++nt)
            acc[nt] = __builtin_amdgcn_mfma_f32_16x16x32_bf16(af, Bf[nt][ks],
                                                              acc[nt], 0, 0, 0);
    }
    // epilogue: D row = quad*4+r, col = c; scale by dinv, store bf16
    size_t R1 = ((size_t)n + 1) * 8;
    #pragma unroll
    for (int r = 0; r < 4; ++r) {
        int node = nb + wv * 16 + quad * 4 + r;
        if (node < n) {
            float d = dinv[node];
            #pragma unroll
            for (int nt = 0; nt < 4; ++nt) {
                __hip_bfloat16 hb = __float2bfloat16(acc[nt][r] * d);
                unsigned short* dst =
                    (unsigned short*)(h1u + (size_t)nt * R1 + (size_t)node * 8) + c;
                *dst = *(unsigned short*)&hb;
            }
        }
    }
}

// ---- conv1: feature-blocked gather pass (gridDim.y = 4 slices). ----
__global__ __launch_bounds__(256, 8) void k_conv1(
        const unsigned* __restrict__ h1u, const int* __restrict__ srcs,
        const int* __restrict__ off, const int* __restrict__ endp,
        const float* __restrict__ dinv, const float* __restrict__ b1,
        unsigned* __restrict__ hu, int n) {
    int lane = threadIdx.x & 63;
    int g = lane >> 3, f = lane & 7, gb = g * 8;
    const unsigned* base = h1u + (size_t)blockIdx.y * (((size_t)n + 1) * 8);
    int node = blockIdx.x * 32 + (threadIdx.x >> 6) * 8 + g;
    int nodec = (node < n) ? node : n;
    int j = (node < n) ? off[node] : 0;
    int e = (node < n) ? endp[node] : 0;
    float a0 = 0.f, a1 = 0.f;
    while (__any(j < e)) {
        int cnt = e - j;
        cnt = cnt < 0 ? 0 : (cnt > 8 ? 8 : cnt);
        int srcv = n;
        if (f < cnt) srcv = srcs[j + f];
        #pragma unroll
        for (int k = 0; k < 8; ++k) {
            int s = __shfl(srcv, gb + k);
            unsigned u = base[(long)s * 8 + f];
            a0 += bflo(u);
            a1 += bfhi(u);
        }
        j += cnt;
    }
    unsigned us = base[(long)nodec * 8 + f];
    float d = (node < n) ? dinv[node] : 0.f;
    float2 bb = ((const float2*)b1)[blockIdx.y * 8 + f];
    float h0 = fmaxf(d * (a0 + bflo(us)) + bb.x, 0.f);
    float h1 = fmaxf(d * (a1 + bfhi(us)) + bb.y, 0.f);
    if (node < n)
        hu[(long)node * 32 + blockIdx.y * 8 + f] = pack2(h0, h1);
}

// ---- h2' = dinv * (h @ W2); output in 2 feature-blocked regions ----
__global__ __launch_bounds__(64) void k_gemm2(
        const unsigned* __restrict__ h32, const float* __restrict__ W2,
        const float* __restrict__ dinv, unsigned* __restrict__ h2u, int n) {
    __shared__ float xl[64 * 66];
    int lane = threadIdx.x;
    int nb = blockIdx.x * 64;
    int tn = lane >> 5;
    int q = lane & 31;
    for (int it = 0; it < 32; ++it) {
        int r = it * 2 + tn;
        int node = nb + r;
        unsigned u = 0;
        if (node < n) u = h32[(long)node * 32 + q];
        xl[r * 66 + 2 * q]     = bflo(u);
        xl[r * 66 + 2 * q + 1] = bfhi(u);
    }
    __syncthreads();
    float acc[F_OUT];
    #pragma unroll
    for (int f = 0; f < F_OUT; ++f) acc[f] = 0.f;
    for (int k = 0; k < F_HID; ++k) {
        float xv = xl[lane * 66 + k];
        const float* wr = W2 + k * F_OUT;
        #pragma unroll
        for (int f = 0; f < F_OUT; ++f) acc[f] = fmaf(xv, wr[f], acc[f]);
    }
    int node = nb + lane;
    if (node < n) {
        float d = dinv[node];
        size_t R2 = ((size_t)n + 1) * 10;
        #pragma unroll
        for (int r = 0; r < 2; ++r)
            #pragma unroll
            for (int t = 0; t < 10; ++t)
                h2u[(size_t)r * R2 + (long)node * 10 + t] =
                    pack2(acc[r * 20 + 2 * t] * d, acc[r * 20 + 2 * t + 1] * d);
    }
}

// ---- conv2: feature-blocked gather pass (gridDim.y = 2 slices). ----
__global__ __launch_bounds__(256, 8) void k_conv2(
        const unsigned* __restrict__ h2u, const int* __restrict__ srcs,
        const int* __restrict__ off, const int* __restrict__ endp,
        const float* __restrict__ dinv, const float* __restrict__ b2,
        float* __restrict__ tmp, int n) {
    int lane = threadIdx.x & 63;
    bool lact = lane < 60;
    int g = lane / 10; if (g > 5) g = 5;
    int f = lane % 10;
    int gb = g * 10;
    const unsigned* base = h2u + (size_t)blockIdx.y * (((size_t)n + 1) * 10);
    int node = blockIdx.x * 24 + (threadIdx.x >> 6) * 6 + g;
    if (!lact) node = n;
    int nodec = (node < n) ? node : n;
    int j = (node < n) ? off[node] : 0;
    int e = (node < n) ? endp[node] : 0;
    float a0 = 0.f, a1 = 0.f;
    while (__any(j < e)) {
        int cnt = e - j;
        cnt = cnt < 0 ? 0 : (cnt > 10 ? 10 : cnt);
        int srcv = n;
        if (f < cnt && lact) srcv = srcs[j + f];
        #pragma unroll
        for (int k = 0; k < 10; ++k) {
            int s = __shfl(srcv, gb + k);
            unsigned u = base[(long)s * 10 + f];
            a0 += bflo(u);
            a1 += bfhi(u);
        }
        j += cnt;
    }
    unsigned us = base[(long)nodec * 10 + f];
    float d = (node < n) ? dinv[node] : 0.f;
    float2 bb = ((const float2*)b2)[blockIdx.y * 10 + f];
    float v0 = d * (a0 + bflo(us)) + bb.x;
    float v1 = d * (a1 + bfhi(us)) + bb.y;
    if (node < n && lact) {
        float2 o;
        o.x = v0; o.y = v1;
        *(float2*)(tmp + (long)node * F_OUT + blockIdx.y * 20 + 2 * f) = o;
    }
}

// ---- log_softmax over the 40 logits of each node; wave per node ----
__global__ __launch_bounds__(256) void k_lsm(const float* __restrict__ tmp,
                                             float* __restrict__ out, int n) {
    int t = blockIdx.x * 256 + threadIdx.x;
    int node = t >> 6, lane = t & 63;
    if (node >= n) return;
    float v = (lane < F_OUT) ? tmp[(long)node * F_OUT + lane] : -INFINITY;
    float m = v;
    #pragma unroll
    for (int o = 32; o > 0; o >>= 1) m = fmaxf(m, __shfl_xor(m, o));
    float ex = (lane < F_OUT) ? expf(v - m) : 0.f;
    float s = ex;
    #pragma unroll
    for (int o = 32; o > 0; o >>= 1) s += __shfl_xor(s, o);
    float lse = logf(s) + m;
    if (lane < F_OUT) out[(long)node * F_OUT + lane] = v - lse;
}

extern "C" void kernel_launch(void* const* d_in, const int* in_sizes, int n_in,
                              void* d_out, int out_size, void* d_ws, size_t ws_size,
                              hipStream_t stream) {
    const float* x     = (const float*)d_in[0];
    const int*   ei    = (const int*)d_in[1];
    const float* gamma = (const float*)d_in[2];
    const float* beta  = (const float*)d_in[3];
    const float* rmean = (const float*)d_in[4];
    const float* rvar  = (const float*)d_in[5];
    const float* W1    = (const float*)d_in[6];
    const float* b1    = (const float*)d_in[7];
    const float* W2    = (const float*)d_in[8];
    const float* b2    = (const float*)d_in[9];
    float* out = (float*)d_out;

    int n = in_sizes[0] / F_IN;
    int E = in_sizes[1] / 2;
    const int* row = ei;       // edge_index[0] = source
    const int* col = ei + E;   // edge_index[1] = target

    int*   deg    = (int*)d_ws;
    int*   off    = deg + n;
    int*   endp   = off + n;
    float* dinv   = (float*)(endp + n);
    int*   cursor = (int*)(dinv + n);                 // 4 ints (16B alignment)
    int*   rank   = cursor + 4;                       // E ints
    int*   srcs   = rank + E;                         // E ints
    unsigned* h1u = (unsigned*)(srcs + E);            // 4 regions x (n+1)*8 dwords
    unsigned* hu  = h1u + 4 * (((size_t)n + 1) * 8);  // n*32 dwords (row-major h)
    unsigned* h2u = hu + (size_t)n * 32;              // 2 regions x (n+1)*10 dwords
    float* tmp    = (float*)h1u;                      // n*40 fp32, aliases dead h1u/hu

    hipMemsetAsync(deg, 0, (size_t)n * sizeof(int), stream);
    hipMemsetAsync(cursor, 0, 4 * sizeof(int), stream);

    k_deg    <<<(E + 255) / 256, 256, 0, stream>>>(col, E, deg, rank);
    k_offsets<<<(n + 255) / 256, 256, 0, stream>>>(deg, off, endp, dinv, cursor, n);
    dim3 ge((E + 255) / 256, 2);
    k_edges  <<<ge, 256, 0, stream>>>(row, col, off, rank, srcs, E, n / 2);
    k_zero   <<<1, 64, 0, stream>>>(h1u, h2u, n);

    k_gemm1<<<(n + 63) / 64, 256, 0, stream>>>(x, gamma, beta, rmean, rvar, W1,
                                               dinv, h1u, n);
    dim3 g1((n + 31) / 32, 4);
    k_conv1<<<g1, 256, 0, stream>>>(h1u, srcs, off, endp, dinv, b1, hu, n);
    k_gemm2<<<(n + 63) / 64, 64, 0, stream>>>(hu, W2, dinv, h2u, n);
    dim3 g2((n + 23) / 24, 2);
    k_conv2<<<g2, 256, 0, stream>>>(h2u, srcs, off, endp, dinv, b2, tmp, n);
    k_lsm  <<<(n + 3) / 4, 256, 0, stream>>>(tmp, out, n);
}